// Round 13
// baseline (3984.347 us; speedup 1.0000x reference)
//
#include <hip/hip_runtime.h>

#define TT 1024
#define DU 256

// workspace layout (bytes)
#define CEX_OFF   0          // u64 tagged c: [8 grp][16 mem][16 b][8 cp] (131072 B)
#define HEX_OFF   131072     // u64 tagged h: same layout (131072 B)
#define STMP_OFF  262144     // u32 stamps PACKED: [8 grp][16 mem][2 wv] (1024 B)
#define TST_OFF   266240     // 8 grp x 4096 B test region (32768 B)
#define GCON_OFF  299008     // gok[128] u32 @ +0; gpol u32 @ +1024 B (2048 B)
#define BLOB_OFF  301056     // 16 member chunks of bf16 weights
#define CHUNK_ELEMS (11*16*256)   // per-member: 11 mats x 16 cols x 256 k

typedef unsigned short ushort_t;
typedef unsigned u32;
typedef unsigned long long u64;
typedef __attribute__((ext_vector_type(8))) short short8;
typedef __attribute__((ext_vector_type(2))) unsigned long long u64x2;
typedef __attribute__((ext_vector_type(4))) float floatx4;

#define MFMA(a, b, c) __builtin_amdgcn_mfma_f32_16x16x32_bf16((a), (b), (c), 0, 0, 0)

__device__ __forceinline__ ushort_t f2bf(float f) {
  unsigned u = __float_as_uint(f);
  return (ushort_t)((u + 0x7fffu + ((u >> 16) & 1u)) >> 16);
}
__device__ __forceinline__ float sigf(float x) { return 1.0f / (1.0f + __expf(-x)); }
__device__ __forceinline__ float tanhf_(float x) {
  float t = 1.0f - 2.0f / (__expf(2.0f * fabsf(x)) + 1.0f);
  return copysignf(t, x);
}

// ================= exchange =================
// Data: u64 per (mem,b,colpair) = (step_tag<<32) | 2 bf16. Stamps: packed
// [mem][wv] words, one per wave. FAST protocol (R13): producer stores data
// then stamp back-to-back with NO ack (tag-verify replaces the ordering ack);
// consumer: cheap stamp poll -> fetch data once -> verify tags -> refetch on
// the rare stamp-outran-data race. Poll BW stays 256B/wave-iter (R12's
// data-as-tag polling at 8KB/iter congested the MALL: 3001->3692).
// SLOW fallback: agent-scope atomics, tag-polled, uncapped (always correct).

__device__ __forceinline__ u32 poll_nt1(const u32* p) {
  u32 s;
  asm volatile("global_load_dword %0, %1, off nt\n\ts_waitcnt vmcnt(0)"
               : "=v"(s) : "v"(p) : "memory");
  return s;
}
// stamp wait: wave wv needs members wv*8..+7, both wave-words each
__device__ __forceinline__ int wait_half_f(const u32* stG, u32 tgt, int lane, int wv) {
  const u32* p = stG + (wv * 8 + (lane & 7)) * 2 + ((lane >> 3) & 1);
  int it = 0;
  for (;;) {
    u32 s = poll_nt1(p);
    if (__all((int)(s >= tgt))) return 1;
    if (++it > 16384) return 0;               // bounded: never hang
  }
}
// fetch this wave's 4 fragments (k-half) and verify embedded tags.
// Entered after the stamp wait -> typically 1 iteration.
__device__ __forceinline__ int fetch_verify_fast(const u64* ex, u32 tag,
                                                 int wv, int lr, int lk, short8 fr[4]) {
  u64x2 q[4][2];
  int it = 0, done = 1;
  for (;;) {
    int ok = 1;
#pragma unroll
    for (int s = 0; s < 4; ++s) {
      int k = wv * 128 + s * 32 + lk * 8;
      const u64* p = ex + ((k >> 4) * 128 + lr * 8 + ((k & 15) >> 1));
      asm volatile("global_load_dwordx4 %0, %2, off nt\n\t"
                   "global_load_dwordx4 %1, %3, off nt\n\t"
                   "s_waitcnt vmcnt(0)"
                   : "=v"(q[s][0]), "=v"(q[s][1])
                   : "v"(p), "v"(p + 2) : "memory");
      ok &= (int)(((u32)(q[s][0][0] >> 32) == tag) & ((u32)(q[s][0][1] >> 32) == tag) &
                  ((u32)(q[s][1][0] >> 32) == tag) & ((u32)(q[s][1][1] >> 32) == tag));
    }
    if (__all(ok)) break;
    if (++it > 16384) { done = 0; break; }
  }
#pragma unroll
  for (int s = 0; s < 4; ++s) {
    union { u32 w[4]; short8 s8; } u;
    u.w[0] = (u32)q[s][0][0]; u.w[1] = (u32)q[s][0][1];
    u.w[2] = (u32)q[s][1][0]; u.w[3] = (u32)q[s][1][1];
    fr[s] = u.s8;
  }
  return done;
}
__device__ __forceinline__ void fetch_slow(const u64* ex, u32 tag,
                                           int wv, int lr, int lk, short8 fr[4]) {
  u64 q[4][4];
  for (;;) {
    int ok = 1;
#pragma unroll
    for (int s = 0; s < 4; ++s) {
      int k = wv * 128 + s * 32 + lk * 8;
      const u64* p = ex + ((k >> 4) * 128 + lr * 8 + ((k & 15) >> 1));
#pragma unroll
      for (int j = 0; j < 4; ++j) {
        q[s][j] = __hip_atomic_load(p + j, __ATOMIC_RELAXED, __HIP_MEMORY_SCOPE_AGENT);
        ok &= (int)((u32)(q[s][j] >> 32) == tag);
      }
    }
    if (__all(ok)) break;
    __builtin_amdgcn_s_sleep(1);
  }
#pragma unroll
  for (int s = 0; s < 4; ++s) {
    union { u32 w[4]; short8 s8; } u;
#pragma unroll
    for (int j = 0; j < 4; ++j) u.w[j] = (u32)q[s][j];
    fr[s] = u.s8;
  }
}
// publish: data store then stamp store, NO ack between (tag-verify covers it)
__device__ __forceinline__ void pub(u64* slot, u32 data, u32 tag,
                                    u32* st, u32 sv, int leader, int mode) {
  u64 v = ((u64)tag << 32) | (u64)data;
  if (mode) {
    asm volatile("global_store_dwordx2 %0, %1, off" :: "v"(slot), "v"(v) : "memory");
    if (leader)
      asm volatile("global_store_dword %0, %1, off" :: "v"(st), "v"(sv) : "memory");
  } else {
    __hip_atomic_store(slot, v, __ATOMIC_RELAXED, __HIP_MEMORY_SCOPE_AGENT);
  }
}

// ---- per-group nt-pipe self-test (3 rounds, fresh data; 4096B/group stride) ----
__device__ int test_nt(u32* tb, int mem, int lane) {
  u64* td = (u64*)tb;
  u32* tstamp = tb + 256;
  u32* tready = tb + 512;
  int ok = 1;
  for (int r = 0; r < 3; ++r) {
    u32 seq = 1u + (u32)r;
    if (lane == 0)
      __hip_atomic_store(tready + mem, seq, __ATOMIC_RELEASE, __HIP_MEMORY_SCOPE_AGENT);
    { int it = 0;
      for (;;) {
        u32 v = __hip_atomic_load(tready + (lane & 15), __ATOMIC_RELAXED,
                                  __HIP_MEMORY_SCOPE_AGENT);
        if (__all((int)(v >= seq))) break;
        if (++it > 16384) return 0;
        __builtin_amdgcn_s_sleep(2);
      } }
    if (lane < 8) {
      u64 v = 0x9E3779B97F4A7C15ull * (u64)(seq * 131u + (u32)mem * 17u + (u32)lane + 1u);
      asm volatile("global_store_dwordx2 %0, %1, off"
                   :: "v"(td + mem * 8 + lane), "v"(v) : "memory");
    }
    asm volatile("s_waitcnt vmcnt(0)" ::: "memory");
    if (lane == 0)
      asm volatile("global_store_dword %0, %1, off"
                   :: "v"(tstamp + mem * 16), "v"(seq) : "memory");
    int saw = 0;
    { int it = 0;
      for (;;) {
        u32 s = poll_nt1(tstamp + (lane & 15) * 16);
        if (__all((int)(s >= seq))) { saw = 1; break; }
        if (++it > 192) break;
        __builtin_amdgcn_s_sleep(2);
      } }
    if (!saw) { ok = 0; continue; }
    u64 a = __builtin_nontemporal_load(td + lane);
    u64 b = __builtin_nontemporal_load(td + lane + 64);
    int s0 = lane >> 3, j0 = lane & 7, s1 = (lane + 64) >> 3, j1 = (lane + 64) & 7;
    u64 e0 = 0x9E3779B97F4A7C15ull * (u64)(seq * 131u + (u32)s0 * 17u + (u32)j0 + 1u);
    u64 e1 = 0x9E3779B97F4A7C15ull * (u64)(seq * 131u + (u32)s1 * 17u + (u32)j1 + 1u);
    if (!__all((int)((a == e0) && (b == e1)))) ok = 0;
  }
  return ok;
}

// ---- weight conversion: blob[mem][mat][col][k] bf16, k contiguous ----
__global__ void conv_weights(
    const float* __restrict__ wf, const float* __restrict__ wi,
    const float* __restrict__ wc, const float* __restrict__ wo,
    const float* __restrict__ rf, const float* __restrict__ ri,
    const float* __restrict__ rc, const float* __restrict__ ro,
    const float* __restrict__ pf, const float* __restrict__ pi,
    const float* __restrict__ po, ushort_t* __restrict__ blob)
{
  int id = blockIdx.x * 256 + threadIdx.x;   // 720896 total, exact
  int k   = id & 255;
  int col = (id >> 8) & 15;
  int q   = id >> 12;          // 0..175
  int m   = q % 11;
  int mm  = q / 11;
  const float* srcs[11] = {wf, wi, wc, wo, rf, ri, rc, ro, pf, pi, po};
  float v = srcs[m][k * 256 + mm * 16 + col];
  unsigned u = __float_as_uint(v);
  blob[id] = (ushort_t)((u + 0x7fffu + ((u >> 16) & 1u)) >> 16);
}

// ---- persistent recurrent kernel (128 blocks, 8 RR groups x 16 members) ----
// R13 = R11 (k-split, best @3001) + no-ack publish with tag-verified fetch.
extern "C" __global__ void __launch_bounds__(128, 1)
lstm_rec(const float* __restrict__ x, const ushort_t* __restrict__ blob,
         u64* __restrict__ h_ex, u64* __restrict__ c_ex,
         u32* __restrict__ stamps, u32* __restrict__ tst, u32* __restrict__ gcon,
         const float* __restrict__ bfv, const float* __restrict__ biv,
         const float* __restrict__ bcv, const float* __restrict__ bov,
         float* __restrict__ out)
{
  __shared__ ushort_t xa[16 * 264];         // x(t) bf16, row stride 264
  __shared__ float pre2[2][2][4][16][17];   // [t&1][wv][gate] k-half partials
  __shared__ float pop2[2][16][17];         // per-wave po partials
  __shared__ float bia[4][16];
  __shared__ int s_mode;

  const int tid = threadIdx.x;
  const int bid = blockIdx.x;
  const int wv = tid >> 6;
  const int lane = tid & 63;
  const int lr = lane & 15;
  const int lk = lane >> 4;

  const int grp = bid & 7;                   // RR grouping (XCD = bid % 8)
  const int mem = bid >> 3;
  const int gb0 = grp * 16;
  const int gc0 = mem * 16;

  u32* gok  = gcon;                          // [128] per-block verdicts
  u32* gpol = gcon + 256;                    // global policy word (own line)

  // ======== transport self-test (wave 0 only; nt flavor) ========
  if (wv == 0) {
    __builtin_amdgcn_fence(__ATOMIC_ACQUIRE, "agent");   // clear cache pre-history
    int okv = test_nt(tst + grp * 1024, mem, lane);
    if (lane == 0)
      __hip_atomic_store(gok + bid, 1u | ((u32)okv << 1),
                         __ATOMIC_RELEASE, __HIP_MEMORY_SCOPE_AGENT);
    if (bid == 0) {
      u32 pol = 0; int it = 0;
      for (;;) {
        u32 a = __hip_atomic_load(gok + lane, __ATOMIC_RELAXED, __HIP_MEMORY_SCOPE_AGENT);
        u32 b = __hip_atomic_load(gok + 64 + lane, __ATOMIC_RELAXED, __HIP_MEMORY_SCOPE_AGENT);
        if (__all((int)((a & 1u) && (b & 1u)))) {
          pol = __all((int)(((a >> 1) & 1u) && ((b >> 1) & 1u))) ? 1u : 0u;
          break;
        }
        if (++it > 32768) { pol = 0; break; }
        __builtin_amdgcn_s_sleep(4);
      }
      if (lane == 0)
        __hip_atomic_store(gpol, pol + 1u, __ATOMIC_RELEASE, __HIP_MEMORY_SCOPE_AGENT);
    }
    u32 p;
    for (;;) {
      p = __hip_atomic_load(gpol, __ATOMIC_RELAXED, __HIP_MEMORY_SCOPE_AGENT);
      if (p) break;
      __builtin_amdgcn_s_sleep(4);
    }
    if (lane == 0) s_mode = (int)(p - 1u);
  }
  __syncthreads();
  const int mode = s_mode;                   // 1 = nt fast, 0 = slow
  int wedged = 0;
  if (mode) __builtin_amdgcn_fence(__ATOMIC_ACQUIRE, "agent");

  // ---- weight fragments -> registers (my k-half of all 11 mats) ----
  const ushort_t* wb = blob + (size_t)mem * CHUNK_ELEMS;
  short8 wW[4][4], wR[4][4], wPf[4], wPi[4], wPo[4];
#pragma unroll
  for (int s = 0; s < 4; ++s) {
    const int ko = wv * 128 + s * 32 + lk * 8;
#pragma unroll
    for (int g = 0; g < 4; ++g) {
      wW[g][s] = *(const short8*)(wb + ((g    ) * 16 + lr) * 256 + ko);
      wR[g][s] = *(const short8*)(wb + ((4 + g) * 16 + lr) * 256 + ko);
    }
    wPf[s] = *(const short8*)(wb + (8  * 16 + lr) * 256 + ko);
    wPi[s] = *(const short8*)(wb + (9  * 16 + lr) * 256 + ko);
    wPo[s] = *(const short8*)(wb + (10 * 16 + lr) * 256 + ko);
  }

  if (tid < 64) {
    const float* bs = (tid < 16) ? bfv : (tid < 32) ? biv : (tid < 48) ? bcv : bov;
    bia[tid >> 4][tid & 15] = bs[gc0 + (tid & 15)];
  }
  const int pb = tid >> 3, pc = (tid & 7) * 2;   // 128 threads x 2 cols = 16x16
  float cr0 = 0.f, cr1 = 0.f;                    // own-c state, f32, registers

  // stage x(0) -> xa (bf16)
  const int xr = tid >> 3, xc = (tid & 7) * 32;
  {
    const float* xp = x + (size_t)(gb0 + xr) * TT * DU + xc;
#pragma unroll
    for (int u = 0; u < 8; ++u) {
      float4 f = *(const float4*)(xp + u * 4);
      *(u64*)&xa[xr * 264 + xc + u * 4] =
          (u64)f2bf(f.x) | ((u64)f2bf(f.y) << 16) |
          ((u64)f2bf(f.z) << 32) | ((u64)f2bf(f.w) << 48);
    }
  }
  __syncthreads();

  const floatx4 z4 = {0.f, 0.f, 0.f, 0.f};
  floatx4 acc[4] = {z4, z4, z4, z4};
  // prologue: x(0)@W for all 4 gates, my k-half (c(-1)=0: no peephole)
#pragma unroll
  for (int s = 0; s < 4; ++s) {
    int k = wv * 128 + s * 32 + lk * 8;
    short8 a = *(const short8*)&xa[lr * 264 + k];
    acc[0] = MFMA(a, wW[0][s], acc[0]);
    acc[1] = MFMA(a, wW[1][s], acc[1]);
    acc[2] = MFMA(a, wW[2][s], acc[2]);
    acc[3] = MFMA(a, wW[3][s], acc[3]);
  }

  u32* stG = stamps + grp * 32;      // packed [mem][wv]
  u64* cG = c_ex + grp * 16 * 128;   // [16 mem][16 b][8 cp] u64
  u64* hG = h_ex + grp * 16 * 128;
  u64* cSlot = cG + mem * 128 + pb * 8 + (tid & 7);
  u64* hSlot = hG + mem * 128 + pb * 8 + (tid & 7);
  u32* mySt  = stG + mem * 2 + wv;

  for (int t = 0; t < TT; ++t) {
    const int tp = t & 1;
    // ---- h-wait (stamps) + tag-verified fetch + h@R, my k-half ----
    if (t > 0) {
      short8 hf[4];
      if (mode) {
        if (!wait_half_f(stG, 2u * (u32)t, lane, wv) && !wedged) wedged = 1;
        if (!fetch_verify_fast(hG, (u32)t, wv, lr, lk, hf) && !wedged) wedged = 1;
      } else {
        fetch_slow(hG, (u32)t, wv, lr, lk, hf);
      }
#pragma unroll
      for (int s = 0; s < 4; ++s) {
        acc[0] = MFMA(hf[s], wR[0][s], acc[0]);
        acc[1] = MFMA(hf[s], wR[1][s], acc[1]);
        acc[2] = MFMA(hf[s], wR[2][s], acc[2]);
        acc[3] = MFMA(hf[s], wR[3][s], acc[3]);
      }
    }
#pragma unroll
    for (int g = 0; g < 4; ++g)
#pragma unroll
      for (int r = 0; r < 4; ++r)
        pre2[tp][wv][g][lk * 4 + r][lr] = acc[g][r];
    __syncthreads();                                  // S1: both halves in

    // ---- pointwise 1 (sum k-half partials) -> publish c (no ack) ----
    {
      float fg = sigf(pre2[tp][0][0][pb][pc] + pre2[tp][1][0][pb][pc] + bia[0][pc]);
      float ig = sigf(pre2[tp][0][1][pb][pc] + pre2[tp][1][1][pb][pc] + bia[1][pc]);
      float ct = tanhf_(pre2[tp][0][2][pb][pc] + pre2[tp][1][2][pb][pc] + bia[2][pc]);
      cr0 = fg * cr0 + ig * ct;
      fg = sigf(pre2[tp][0][0][pb][pc + 1] + pre2[tp][1][0][pb][pc + 1] + bia[0][pc + 1]);
      ig = sigf(pre2[tp][0][1][pb][pc + 1] + pre2[tp][1][1][pb][pc + 1] + bia[1][pc + 1]);
      ct = tanhf_(pre2[tp][0][2][pb][pc + 1] + pre2[tp][1][2][pb][pc + 1] + bia[2][pc + 1]);
      cr1 = fg * cr1 + ig * ct;
    }
    pub(cSlot, (u32)f2bf(cr0) | ((u32)f2bf(cr1) << 16), (u32)t + 1u,
        mySt, 2u * (u32)t + 1u, lane == 0, mode);

    // ---- x(t+1): issue + stage fills the c-window ----
    if (t < TT - 1) {
      float4 xf[8];
      const float* xp = x + ((size_t)(gb0 + xr) * TT + (t + 1)) * DU + xc;
#pragma unroll
      for (int u = 0; u < 8; ++u) xf[u] = *(const float4*)(xp + u * 4);
#pragma unroll
      for (int u = 0; u < 8; ++u) {
        float4 f = xf[u];
        *(u64*)&xa[xr * 264 + xc + u * 4] =
            (u64)f2bf(f.x) | ((u64)f2bf(f.y) << 16) |
            ((u64)f2bf(f.z) << 32) | ((u64)f2bf(f.w) << 48);
      }
      __syncthreads();                                // S8: xa ready
    }

    // ---- c-wait (stamps) + tag-verified fetch + phase B: 4 po MFMA ----
    short8 cf[4];
    if (mode) {
      if (!wait_half_f(stG, 2u * (u32)t + 1u, lane, wv) && !wedged) wedged = 1;
      if (!fetch_verify_fast(cG, (u32)t + 1u, wv, lr, lk, cf) && !wedged) wedged = 1;
    } else {
      fetch_slow(cG, (u32)t + 1u, wv, lr, lk, cf);
    }
    {
      floatx4 pacc = z4;
#pragma unroll
      for (int s = 0; s < 4; ++s) pacc = MFMA(cf[s], wPo[s], pacc);
#pragma unroll
      for (int r = 0; r < 4; ++r) pop2[wv][lk * 4 + r][lr] = pacc[r];
    }
    __syncthreads();                                  // S5: both po halves in

    // ---- pointwise 2 -> publish h (no ack) ----
    float og0 = sigf(pre2[tp][0][3][pb][pc] + pre2[tp][1][3][pb][pc]
                   + pop2[0][pb][pc] + pop2[1][pb][pc] + bia[3][pc]);
    float hv0 = tanhf_(cr0) * og0;
    float og1 = sigf(pre2[tp][0][3][pb][pc + 1] + pre2[tp][1][3][pb][pc + 1]
                   + pop2[0][pb][pc + 1] + pop2[1][pb][pc + 1] + bia[3][pc + 1]);
    float hv1 = tanhf_(cr1) * og1;
    if (t == TT - 1) {
      float2 o2; o2.x = hv0; o2.y = hv1;
      *(float2*)&out[(gb0 + pb) * 256 + gc0 + pc] = o2;
      break;
    }
    pub(hSlot, (u32)f2bf(hv0) | ((u32)f2bf(hv1) << 16), (u32)t + 1u,
        mySt, 2u * (u32)t + 2u, lane == 0, mode);

    // ---- h-window: x(t+1)@W + pf/pi peepholes (cf already in regs) ----
#pragma unroll
    for (int g = 0; g < 4; ++g) acc[g] = z4;
#pragma unroll
    for (int s = 0; s < 4; ++s) {
      int k = wv * 128 + s * 32 + lk * 8;
      short8 a = *(const short8*)&xa[lr * 264 + k];
      acc[0] = MFMA(a, wW[0][s], acc[0]);
      acc[1] = MFMA(a, wW[1][s], acc[1]);
      acc[2] = MFMA(a, wW[2][s], acc[2]);
      acc[3] = MFMA(a, wW[3][s], acc[3]);
    }
#pragma unroll
    for (int s = 0; s < 4; ++s) {
      acc[0] = MFMA(cf[s], wPf[s], acc[0]);            // c(t)@pf
      acc[1] = MFMA(cf[s], wPi[s], acc[1]);            // c(t)@pi
    }
  }
}

extern "C" void kernel_launch(void* const* d_in, const int* in_sizes, int n_in,
                              void* d_out, int out_size, void* d_ws, size_t ws_size,
                              hipStream_t stream) {
  const float* x   = (const float*)d_in[0];
  const float* bfv = (const float*)d_in[12];
  const float* biv = (const float*)d_in[13];
  const float* bcv = (const float*)d_in[14];
  const float* bov = (const float*)d_in[15];
  float* outp = (float*)d_out;

  char* ws = (char*)d_ws;
  u64* c_exp = (u64*)(ws + CEX_OFF);
  u64* h_exp = (u64*)(ws + HEX_OFF);
  u32* stmp = (u32*)(ws + STMP_OFF);
  u32* tstp = (u32*)(ws + TST_OFF);
  u32* gcon = (u32*)(ws + GCON_OFF);
  ushort_t* blob = (ushort_t*)(ws + BLOB_OFF);

  // zero tagged exchange buffers + stamps + test/consensus regions (tags and
  // stamps must restart at 0 every replay)
  hipMemsetAsync(d_ws, 0, BLOB_OFF, stream);

  hipLaunchKernelGGL(conv_weights, dim3(2816), dim3(256), 0, stream,
                     (const float*)d_in[1], (const float*)d_in[2],
                     (const float*)d_in[3], (const float*)d_in[4],
                     (const float*)d_in[5], (const float*)d_in[6],
                     (const float*)d_in[7], (const float*)d_in[8],
                     (const float*)d_in[9], (const float*)d_in[10],
                     (const float*)d_in[11], blob);

  hipLaunchKernelGGL(lstm_rec, dim3(128), dim3(128), 0, stream,
                     x, (const ushort_t*)blob, h_exp, c_exp, stmp, tstp, gcon,
                     bfv, biv, bcv, bov, outp);
}

// Round 14
// 2986.535 us; speedup vs baseline: 1.3341x; 1.3341x over previous
//
#include <hip/hip_runtime.h>

#define TT 1024
#define DU 256

// workspace layout (bytes)
#define CEX_OFF   0          // bf16 c slots: [8 grp][16 mem][16 b][16 c] (65536 B)
#define HEX_OFF   65536      // bf16 h slots: same layout (65536 B)
#define STMP_OFF  131072     // u32 stamps PACKED: [8 grp][16 mem][2 wv] (1024 B)
#define TST_OFF   139264     // 8 grp x 4096 B test region (32768 B)
#define GCON_OFF  172032     // gok[128] u32 @ +0; gpol u32 @ +1024 B (2048 B)
#define BLOB_OFF  174080     // 16 member chunks of bf16 weights
#define CHUNK_ELEMS (11*16*256)   // per-member: 11 mats x 16 cols x 256 k

typedef unsigned short ushort_t;
typedef unsigned u32;
typedef unsigned long long u64;
typedef __attribute__((ext_vector_type(8))) short short8;
typedef __attribute__((ext_vector_type(2))) unsigned long long u64x2;
typedef __attribute__((ext_vector_type(4))) float floatx4;

#define MFMA(a, b, c) __builtin_amdgcn_mfma_f32_16x16x32_bf16((a), (b), (c), 0, 0, 0)

__device__ __forceinline__ ushort_t f2bf(float f) {
  unsigned u = __float_as_uint(f);
  return (ushort_t)((u + 0x7fffu + ((u >> 16) & 1u)) >> 16);
}
__device__ __forceinline__ float sigf(float x) { return 1.0f / (1.0f + __expf(-x)); }
__device__ __forceinline__ float tanhf_(float x) {
  float t = 1.0f - 2.0f / (__expf(2.0f * fabsf(x)) + 1.0f);
  return copysignf(t, x);
}

// ---------------- slow (agent/MALL) exchange: proven fallback ----------------
__device__ __forceinline__ short8 ldfrag(const ushort_t* p) {
  union { struct { u64 a, b; } q; short8 s; } v;
  v.q.a = __hip_atomic_load((const u64*)p,       __ATOMIC_RELAXED, __HIP_MEMORY_SCOPE_AGENT);
  v.q.b = __hip_atomic_load((const u64*)(p + 4), __ATOMIC_RELAXED, __HIP_MEMORY_SCOPE_AGENT);
  return v.s;
}
// half-wait: wave wv needs only members wv*8..wv*8+7, both wave-words each
__device__ __forceinline__ void wait_half_slow(const u32* stG, u32 tgt, int lane, int wv) {
  const u32* p = stG + (wv * 8 + (lane & 7)) * 2 + ((lane >> 3) & 1);
  for (;;) {
    u32 s = __hip_atomic_load(p, __ATOMIC_RELAXED, __HIP_MEMORY_SCOPE_AGENT);
    if (__all((int)(s >= tgt))) return;
    __builtin_amdgcn_s_sleep(1);
  }
}

// ---------------- fast (nt, MALL-mediated) exchange — R5/R8/R9/R11-proven ----------------
// Producer: plain data stores -> vmcnt(0) ack -> plain stamp store. Consumer:
// cheap stamp poll (256B/wave-iter) -> single plain nt fetch. PROTOCOL IS
// MEASURED-OPTIMAL: R12 (poll data-as-tags, 8KB/iter) congested the MALL
// (3001->3692); R13 (no ack, tag-verify) let stamps race ahead of data,
// forcing fetch retries (3001->3984). The ack orders data-before-stamp so
// exactly ONE fetch suffices.
__device__ __forceinline__ u32 poll_nt(const u32* p) {
  u32 s;
  asm volatile("global_load_dword %0, %1, off nt\n\ts_waitcnt vmcnt(0)"
               : "=v"(s) : "v"(p) : "memory");
  return s;
}
__device__ __forceinline__ int wait_half_f(const u32* stG, u32 tgt, int lane, int wv) {
  const u32* p = stG + (wv * 8 + (lane & 7)) * 2 + ((lane >> 3) & 1);
  int it = 0;
  for (;;) {                                  // tight poll, bounded
    u32 s = poll_nt(p);
    if (__all((int)(s >= tgt))) return 1;
    if (++it > 16384) return 0;
  }
}
// nt 16B fragment load — builtin so the compiler pipelines with MFMAs
__device__ __forceinline__ short8 ldfrag_nt(const ushort_t* p) {
  union { u64x2 q; short8 s; } v;
  v.q = __builtin_nontemporal_load((const u64x2*)p);
  return v.s;
}

// ---- per-group nt-pipe self-test (3 rounds, fresh data; 4096B/group stride) ----
__device__ int test_nt(u32* tb, int mem, int lane) {
  u64* td = (u64*)tb;
  u32* tstamp = tb + 256;
  u32* tready = tb + 512;
  int ok = 1;
  for (int r = 0; r < 3; ++r) {
    u32 seq = 1u + (u32)r;
    if (lane == 0)
      __hip_atomic_store(tready + mem, seq, __ATOMIC_RELEASE, __HIP_MEMORY_SCOPE_AGENT);
    { int it = 0;
      for (;;) {
        u32 v = __hip_atomic_load(tready + (lane & 15), __ATOMIC_RELAXED,
                                  __HIP_MEMORY_SCOPE_AGENT);
        if (__all((int)(v >= seq))) break;
        if (++it > 16384) return 0;
        __builtin_amdgcn_s_sleep(2);
      } }
    if (lane < 8) {
      u64 v = 0x9E3779B97F4A7C15ull * (u64)(seq * 131u + (u32)mem * 17u + (u32)lane + 1u);
      asm volatile("global_store_dwordx2 %0, %1, off"
                   :: "v"(td + mem * 8 + lane), "v"(v) : "memory");
    }
    asm volatile("s_waitcnt vmcnt(0)" ::: "memory");
    if (lane == 0)
      asm volatile("global_store_dword %0, %1, off"
                   :: "v"(tstamp + mem * 16), "v"(seq) : "memory");
    int saw = 0;
    { int it = 0;
      for (;;) {
        u32 s = poll_nt(tstamp + (lane & 15) * 16);
        if (__all((int)(s >= seq))) { saw = 1; break; }
        if (++it > 192) break;
        __builtin_amdgcn_s_sleep(2);
      } }
    if (!saw) { ok = 0; continue; }
    u64 a = __builtin_nontemporal_load(td + lane);
    u64 b = __builtin_nontemporal_load(td + lane + 64);
    int s0 = lane >> 3, j0 = lane & 7, s1 = (lane + 64) >> 3, j1 = (lane + 64) & 7;
    u64 e0 = 0x9E3779B97F4A7C15ull * (u64)(seq * 131u + (u32)s0 * 17u + (u32)j0 + 1u);
    u64 e1 = 0x9E3779B97F4A7C15ull * (u64)(seq * 131u + (u32)s1 * 17u + (u32)j1 + 1u);
    if (!__all((int)((a == e0) && (b == e1)))) ok = 0;
  }
  return ok;
}

// ---- weight conversion: blob[mem][mat][col][k] bf16, k contiguous ----
__global__ void conv_weights(
    const float* __restrict__ wf, const float* __restrict__ wi,
    const float* __restrict__ wc, const float* __restrict__ wo,
    const float* __restrict__ rf, const float* __restrict__ ri,
    const float* __restrict__ rc, const float* __restrict__ ro,
    const float* __restrict__ pf, const float* __restrict__ pi,
    const float* __restrict__ po, ushort_t* __restrict__ blob)
{
  int id = blockIdx.x * 256 + threadIdx.x;   // 720896 total, exact
  int k   = id & 255;
  int col = (id >> 8) & 15;
  int q   = id >> 12;          // 0..175
  int m   = q % 11;
  int mm  = q / 11;
  const float* srcs[11] = {wf, wi, wc, wo, rf, ri, rc, ro, pf, pi, po};
  float v = srcs[m][k * 256 + mm * 16 + col];
  unsigned u = __float_as_uint(v);
  blob[id] = (ushort_t)((u + 0x7fffu + ((u >> 16) & 1u)) >> 16);
}

// ---- persistent recurrent kernel (128 blocks, 8 RR groups x 16 members) ----
// R14 = R11 (best measured: 3001 us) + pre2 parity double-buffering (closes a
// formal cross-iteration LDS race; perf-neutral). Structure: k-split across
// waves — wave wv contracts U-half wv*128..+127 for ALL 4 gates; partials
// summed via pre2/pop2; pf/pi peepholes in the h-window; phase B = 4 po MFMA.
extern "C" __global__ void __launch_bounds__(128, 1)
lstm_rec(const float* __restrict__ x, const ushort_t* __restrict__ blob,
         ushort_t* __restrict__ h_ex, ushort_t* __restrict__ c_ex,
         u32* __restrict__ stamps, u32* __restrict__ tst, u32* __restrict__ gcon,
         const float* __restrict__ bfv, const float* __restrict__ biv,
         const float* __restrict__ bcv, const float* __restrict__ bov,
         float* __restrict__ out)
{
  __shared__ ushort_t xa[16 * 264];         // x(t) bf16, row stride 264
  __shared__ float pre2[2][2][4][16][17];   // [t&1][wv][gate] k-half partials
  __shared__ float pop2[2][16][17];         // per-wave po partials
  __shared__ float bia[4][16];
  __shared__ int s_mode;

  const int tid = threadIdx.x;
  const int bid = blockIdx.x;
  const int wv = tid >> 6;
  const int lane = tid & 63;
  const int lr = lane & 15;
  const int lk = lane >> 4;

  const int grp = bid & 7;                   // RR grouping (XCD = bid % 8)
  const int mem = bid >> 3;
  const int gb0 = grp * 16;
  const int gc0 = mem * 16;

  u32* gok  = gcon;                          // [128] per-block verdicts
  u32* gpol = gcon + 256;                    // global policy word (own line)

  // ======== transport self-test (wave 0 only; nt flavor) ========
  if (wv == 0) {
    __builtin_amdgcn_fence(__ATOMIC_ACQUIRE, "agent");   // clear cache pre-history
    int okv = test_nt(tst + grp * 1024, mem, lane);
    if (lane == 0)
      __hip_atomic_store(gok + bid, 1u | ((u32)okv << 1),
                         __ATOMIC_RELEASE, __HIP_MEMORY_SCOPE_AGENT);
    if (bid == 0) {
      u32 pol = 0; int it = 0;
      for (;;) {
        u32 a = __hip_atomic_load(gok + lane, __ATOMIC_RELAXED, __HIP_MEMORY_SCOPE_AGENT);
        u32 b = __hip_atomic_load(gok + 64 + lane, __ATOMIC_RELAXED, __HIP_MEMORY_SCOPE_AGENT);
        if (__all((int)((a & 1u) && (b & 1u)))) {
          pol = __all((int)(((a >> 1) & 1u) && ((b >> 1) & 1u))) ? 1u : 0u;
          break;
        }
        if (++it > 32768) { pol = 0; break; }
        __builtin_amdgcn_s_sleep(4);
      }
      if (lane == 0)
        __hip_atomic_store(gpol, pol + 1u, __ATOMIC_RELEASE, __HIP_MEMORY_SCOPE_AGENT);
    }
    u32 p;
    for (;;) {
      p = __hip_atomic_load(gpol, __ATOMIC_RELAXED, __HIP_MEMORY_SCOPE_AGENT);
      if (p) break;
      __builtin_amdgcn_s_sleep(4);
    }
    if (lane == 0) s_mode = (int)(p - 1u);
  }
  __syncthreads();
  const int mode = s_mode;                   // 1 = nt fast, 0 = slow
  int wedged = 0;
  if (mode) __builtin_amdgcn_fence(__ATOMIC_ACQUIRE, "agent");

  // ---- weight fragments -> registers (my k-half of all 11 mats) ----
  const ushort_t* wb = blob + (size_t)mem * CHUNK_ELEMS;
  short8 wW[4][4], wR[4][4], wPf[4], wPi[4], wPo[4];
#pragma unroll
  for (int s = 0; s < 4; ++s) {
    const int ko = wv * 128 + s * 32 + lk * 8;
#pragma unroll
    for (int g = 0; g < 4; ++g) {
      wW[g][s] = *(const short8*)(wb + ((g    ) * 16 + lr) * 256 + ko);
      wR[g][s] = *(const short8*)(wb + ((4 + g) * 16 + lr) * 256 + ko);
    }
    wPf[s] = *(const short8*)(wb + (8  * 16 + lr) * 256 + ko);
    wPi[s] = *(const short8*)(wb + (9  * 16 + lr) * 256 + ko);
    wPo[s] = *(const short8*)(wb + (10 * 16 + lr) * 256 + ko);
  }

  if (tid < 64) {
    const float* bs = (tid < 16) ? bfv : (tid < 32) ? biv : (tid < 48) ? bcv : bov;
    bia[tid >> 4][tid & 15] = bs[gc0 + (tid & 15)];
  }
  const int pb = tid >> 3, pc = (tid & 7) * 2;   // 128 threads x 2 cols = 16x16
  float cr0 = 0.f, cr1 = 0.f;                    // own-c state, f32, registers

  // stage x(0) -> xa (bf16)
  const int xr = tid >> 3, xc = (tid & 7) * 32;
  {
    const float* xp = x + (size_t)(gb0 + xr) * TT * DU + xc;
#pragma unroll
    for (int u = 0; u < 8; ++u) {
      float4 f = *(const float4*)(xp + u * 4);
      *(u64*)&xa[xr * 264 + xc + u * 4] =
          (u64)f2bf(f.x) | ((u64)f2bf(f.y) << 16) |
          ((u64)f2bf(f.z) << 32) | ((u64)f2bf(f.w) << 48);
    }
  }
  __syncthreads();

  const floatx4 z4 = {0.f, 0.f, 0.f, 0.f};
  floatx4 acc[4] = {z4, z4, z4, z4};
  // prologue: x(0)@W for all 4 gates, my k-half (c(-1)=0: no peephole)
#pragma unroll
  for (int s = 0; s < 4; ++s) {
    int k = wv * 128 + s * 32 + lk * 8;
    short8 a = *(const short8*)&xa[lr * 264 + k];
    acc[0] = MFMA(a, wW[0][s], acc[0]);
    acc[1] = MFMA(a, wW[1][s], acc[1]);
    acc[2] = MFMA(a, wW[2][s], acc[2]);
    acc[3] = MFMA(a, wW[3][s], acc[3]);
  }

  u32* stG = stamps + grp * 32;           // packed: [mem][wv]
  ushort_t* cG = c_ex + grp * 16 * 256;   // 16 slots x 256 ushorts
  ushort_t* hG = h_ex + grp * 16 * 256;
  u32* cSlot = (u32*)(cG + mem * 256 + pb * 16 + pc);
  u32* hSlot = (u32*)(hG + mem * 256 + pb * 16 + pc);
  u32* mySt  = stG + mem * 2 + wv;

  for (int t = 0; t < TT; ++t) {
    const int tp = t & 1;
    // ---- h-wait (my 8 members) + h@R for all gates, my k-half ----
    if (t > 0) {
      if (mode) { if (!wedged && !wait_half_f(stG, 2u * (u32)t, lane, wv)) wedged = 1; }
      else wait_half_slow(stG, 2u * (u32)t, lane, wv);
      short8 hf[4];
#pragma unroll
      for (int s = 0; s < 4; ++s) {
        int k = wv * 128 + s * 32 + lk * 8;
        hf[s] = mode ? ldfrag_nt(hG + (k >> 4) * 256 + lr * 16 + (k & 15))
                     : ldfrag(hG + (k >> 4) * 256 + lr * 16 + (k & 15));
      }
#pragma unroll
      for (int s = 0; s < 4; ++s) {
        acc[0] = MFMA(hf[s], wR[0][s], acc[0]);
        acc[1] = MFMA(hf[s], wR[1][s], acc[1]);
        acc[2] = MFMA(hf[s], wR[2][s], acc[2]);
        acc[3] = MFMA(hf[s], wR[3][s], acc[3]);
      }
    }
#pragma unroll
    for (int g = 0; g < 4; ++g)
#pragma unroll
      for (int r = 0; r < 4; ++r)
        pre2[tp][wv][g][lk * 4 + r][lr] = acc[g][r];
    __syncthreads();                                  // S1: both halves in

    // ---- pointwise 1 (sum the two k-half partials) -> publish c ----
    {
      float fg = sigf(pre2[tp][0][0][pb][pc] + pre2[tp][1][0][pb][pc] + bia[0][pc]);
      float ig = sigf(pre2[tp][0][1][pb][pc] + pre2[tp][1][1][pb][pc] + bia[1][pc]);
      float ct = tanhf_(pre2[tp][0][2][pb][pc] + pre2[tp][1][2][pb][pc] + bia[2][pc]);
      cr0 = fg * cr0 + ig * ct;
      fg = sigf(pre2[tp][0][0][pb][pc + 1] + pre2[tp][1][0][pb][pc + 1] + bia[0][pc + 1]);
      ig = sigf(pre2[tp][0][1][pb][pc + 1] + pre2[tp][1][1][pb][pc + 1] + bia[1][pc + 1]);
      ct = tanhf_(pre2[tp][0][2][pb][pc + 1] + pre2[tp][1][2][pb][pc + 1] + bia[2][pc + 1]);
      cr1 = fg * cr1 + ig * ct;
    }
    {
      u32 cw = (u32)f2bf(cr0) | ((u32)f2bf(cr1) << 16);
      if (mode)
        asm volatile("global_store_dword %0, %1, off" :: "v"(cSlot), "v"(cw) : "memory");
      else
        __hip_atomic_store(cSlot, cw, __ATOMIC_RELAXED, __HIP_MEMORY_SCOPE_AGENT);
      asm volatile("s_waitcnt vmcnt(0)" ::: "memory");  // c-store ack only
      if (lane == 0) {
        u32 sv = 2u * (u32)t + 1u;
        if (mode)
          asm volatile("global_store_dword %0, %1, off" :: "v"(mySt), "v"(sv) : "memory");
        else
          __hip_atomic_store(mySt, sv, __ATOMIC_RELAXED, __HIP_MEMORY_SCOPE_AGENT);
      }
    }

    // ---- x(t+1): issue after the stamp; stage fills the c-window ----
    if (t < TT - 1) {
      float4 xf[8];
      const float* xp = x + ((size_t)(gb0 + xr) * TT + (t + 1)) * DU + xc;
#pragma unroll
      for (int u = 0; u < 8; ++u) xf[u] = *(const float4*)(xp + u * 4);
#pragma unroll
      for (int u = 0; u < 8; ++u) {
        float4 f = xf[u];
        *(u64*)&xa[xr * 264 + xc + u * 4] =
            (u64)f2bf(f.x) | ((u64)f2bf(f.y) << 16) |
            ((u64)f2bf(f.z) << 32) | ((u64)f2bf(f.w) << 48);
      }
      __syncthreads();                                // S8: xa ready
    }

    // ---- c-wait (my 8 members; clean polls) ----
    if (mode) { if (!wedged && !wait_half_f(stG, 2u * (u32)t + 1u, lane, wv)) wedged = 1; }
    else wait_half_slow(stG, 2u * (u32)t + 1u, lane, wv);

    // ---- phase B (critical): po partial only — 4 MFMA ----
    short8 cf[4];
#pragma unroll
    for (int s = 0; s < 4; ++s) {
      int k = wv * 128 + s * 32 + lk * 8;
      cf[s] = mode ? ldfrag_nt(cG + (k >> 4) * 256 + lr * 16 + (k & 15))
                   : ldfrag(cG + (k >> 4) * 256 + lr * 16 + (k & 15));
    }
    {
      floatx4 pacc = z4;
#pragma unroll
      for (int s = 0; s < 4; ++s) pacc = MFMA(cf[s], wPo[s], pacc);
#pragma unroll
      for (int r = 0; r < 4; ++r) pop2[wv][lk * 4 + r][lr] = pacc[r];
    }
    __syncthreads();                                  // S5: both po halves in

    // ---- pointwise 2 -> publish h ----
    float og0 = sigf(pre2[tp][0][3][pb][pc] + pre2[tp][1][3][pb][pc]
                   + pop2[0][pb][pc] + pop2[1][pb][pc] + bia[3][pc]);
    float hv0 = tanhf_(cr0) * og0;
    float og1 = sigf(pre2[tp][0][3][pb][pc + 1] + pre2[tp][1][3][pb][pc + 1]
                   + pop2[0][pb][pc + 1] + pop2[1][pb][pc + 1] + bia[3][pc + 1]);
    float hv1 = tanhf_(cr1) * og1;
    if (t == TT - 1) {
      float2 o2; o2.x = hv0; o2.y = hv1;
      *(float2*)&out[(gb0 + pb) * 256 + gc0 + pc] = o2;
      break;
    }
    {
      u32 hw = (u32)f2bf(hv0) | ((u32)f2bf(hv1) << 16);
      if (mode)
        asm volatile("global_store_dword %0, %1, off" :: "v"(hSlot), "v"(hw) : "memory");
      else
        __hip_atomic_store(hSlot, hw, __ATOMIC_RELAXED, __HIP_MEMORY_SCOPE_AGENT);
      asm volatile("s_waitcnt vmcnt(0)" ::: "memory");  // h-store ack only
      if (lane == 0) {
        u32 sv = 2u * (u32)t + 2u;
        if (mode)
          asm volatile("global_store_dword %0, %1, off" :: "v"(mySt), "v"(sv) : "memory");
        else
          __hip_atomic_store(mySt, sv, __ATOMIC_RELAXED, __HIP_MEMORY_SCOPE_AGENT);
      }
    }

    // ---- h-window: x(t+1)@W + pf/pi peepholes (cf already in regs) ----
#pragma unroll
    for (int g = 0; g < 4; ++g) acc[g] = z4;
#pragma unroll
    for (int s = 0; s < 4; ++s) {
      int k = wv * 128 + s * 32 + lk * 8;
      short8 a = *(const short8*)&xa[lr * 264 + k];
      acc[0] = MFMA(a, wW[0][s], acc[0]);
      acc[1] = MFMA(a, wW[1][s], acc[1]);
      acc[2] = MFMA(a, wW[2][s], acc[2]);
      acc[3] = MFMA(a, wW[3][s], acc[3]);
    }
#pragma unroll
    for (int s = 0; s < 4; ++s) {
      acc[0] = MFMA(cf[s], wPf[s], acc[0]);            // c(t)@pf
      acc[1] = MFMA(cf[s], wPi[s], acc[1]);            // c(t)@pi
    }
  }
}

extern "C" void kernel_launch(void* const* d_in, const int* in_sizes, int n_in,
                              void* d_out, int out_size, void* d_ws, size_t ws_size,
                              hipStream_t stream) {
  const float* x   = (const float*)d_in[0];
  const float* bfv = (const float*)d_in[12];
  const float* biv = (const float*)d_in[13];
  const float* bcv = (const float*)d_in[14];
  const float* bov = (const float*)d_in[15];
  float* outp = (float*)d_out;

  char* ws = (char*)d_ws;
  ushort_t* c_exp = (ushort_t*)(ws + CEX_OFF);
  ushort_t* h_exp = (ushort_t*)(ws + HEX_OFF);
  u32* stmp = (u32*)(ws + STMP_OFF);
  u32* tstp = (u32*)(ws + TST_OFF);
  u32* gcon = (u32*)(ws + GCON_OFF);
  ushort_t* blob = (ushort_t*)(ws + BLOB_OFF);

  // zero exchange buffers + stamps + test/consensus regions (restart every replay)
  hipMemsetAsync(d_ws, 0, BLOB_OFF, stream);

  hipLaunchKernelGGL(conv_weights, dim3(2816), dim3(256), 0, stream,
                     (const float*)d_in[1], (const float*)d_in[2],
                     (const float*)d_in[3], (const float*)d_in[4],
                     (const float*)d_in[5], (const float*)d_in[6],
                     (const float*)d_in[7], (const float*)d_in[8],
                     (const float*)d_in[9], (const float*)d_in[10],
                     (const float*)d_in[11], blob);

  hipLaunchKernelGGL(lstm_rec, dim3(128), dim3(128), 0, stream,
                     x, (const ushort_t*)blob, h_exp, c_exp, stmp, tstp, gcon,
                     bfv, biv, bcv, bov, outp);
}